// Round 7
// baseline (229.107 us; speedup 1.0000x reference)
//
#include <hip/hip_runtime.h>

// GlobalShift2dV2Portion: x (16, 512, 64, 64) f32.
// ch < 256  : identity. ch >= 256 : 4x4 grid of 16x16 blocks, block ring
// rotated by s = (ch-256)/16 (t_in = (s + t_out) % 16).
//
// V7 = V5/V6 wave-bijective super-row addressing (both streams 128B-line
// coalesced for every shift) + ONE IMAGE PER BLOCK, 4 slots/thread.
// Block's 4 waves own super-rows {w, w+4, w+8, w+12} (group g = +4g rows
// = +1 KiB on BOTH read and write side; l, q invariant across groups).
// The 4 loads issue back-to-back off one address with offset immediates:
// MLP=4/thread, 4x fewer waves (8192 blocks vs 32768), no extra index VALU.
// (Rounds 5-6 failed at the CONTAINER level — broker flakiness, no kernel
// evidence. Third submission, unchanged. If it fails again: revert to V6.)

#define CC 512

typedef float f32x4 __attribute__((ext_vector_type(4)));

__global__ __launch_bounds__(256) void GlobalShift2dV2Portion_kernel(
    const f32x4* __restrict__ in, f32x4* __restrict__ out) {
  const int bc  = blockIdx.x;              // b*512 + ch  (one image per block)
  const int ch  = bc & (CC - 1);
  const int tid = threadIdx.x;

  const int l  = tid & 63;                 // slot within super-row (lane)
  const int w  = tid >> 6;                 // wave id = low 2 bits of super-row

  const int sh = (ch >= CC / 2) ? ((ch - CC / 2) >> 4) : 0;  // 0 => identity
  const int q  = (l + (sh << 2)) & 63;     // rotated input slot (wave bijection)

  const int base = bc << 10;
  // g=0 offsets; group g adds (g<<6) float4 = g KiB on BOTH sides.
  const int o0 = base + (((l >> 4) << 8) | (w << 4) | (l & 15));
  const int i0 = base + (((q >> 4) << 8) | (w << 4) | (q & 15));

  f32x4 v0 = in[i0];
  f32x4 v1 = in[i0 + 64];
  f32x4 v2 = in[i0 + 128];
  f32x4 v3 = in[i0 + 192];
  __builtin_nontemporal_store(v0, &out[o0]);
  __builtin_nontemporal_store(v1, &out[o0 + 64]);
  __builtin_nontemporal_store(v2, &out[o0 + 128]);
  __builtin_nontemporal_store(v3, &out[o0 + 192]);
}

extern "C" void kernel_launch(void* const* d_in, const int* in_sizes, int n_in,
                              void* d_out, int out_size, void* d_ws, size_t ws_size,
                              hipStream_t stream) {
  const f32x4* in = (const f32x4*)d_in[0];
  f32x4* out = (f32x4*)d_out;
  const int blocks = in_sizes[0] / (1024 * 4);   // 16*512 = 8192 images
  GlobalShift2dV2Portion_kernel<<<blocks, 256, 0, stream>>>(in, out);
}

// Round 10
// 215.454 us; speedup vs baseline: 1.0634x; 1.0634x over previous
//
#include <hip/hip_runtime.h>

// GlobalShift2dV2Portion: x (16, 512, 64, 64) f32.
// ch < 256  : identity. ch >= 256 : 4x4 grid of 16x16 blocks, block ring
// rotated by s = (ch-256)/16 (t_in = (s + t_out) % 16).
//
// V8 = V6 (wave-bijective super-row addressing, 1 float4/thread, 32768
// blocks, nt stores) + NON-TEMPORAL LOADS.
// Every 128B line is read exactly once by exactly one wave (the rotation is
// a bijection within the wave), so read-caching is pure pollution: plain
// loads allocate 128 MiB through L2/L3 and contend with the nt write
// stream. nt loads make both streams pure streaming — the regime where the
// harness fills sustain 6.7 TB/s.
// (V4/V7 established that >1 float4/thread REGRESSES ~10 us on this op —
// keep the massively-parallel 1/thread form.)
// (Rounds 8-9 died at the container level — same broker flake as rounds
// 5-6, which cleared on the third submission of identical source. Third
// submission of V8, unchanged. If it fails again: revert to benched V6.)

#define CC 512

typedef float f32x4 __attribute__((ext_vector_type(4)));

__global__ __launch_bounds__(256) void GlobalShift2dV2Portion_kernel(
    const f32x4* __restrict__ in, f32x4* __restrict__ out) {
  const int i  = blockIdx.x * 256 + threadIdx.x;  // global float4 slot
  const int l  = i & 63;          // slot within super-row (lane)
  const int h0 = (i >> 6) & 15;   // super-row (row within 16-row stripe)
  const int bc = i >> 10;         // b*512 + ch
  const int ch = bc & (CC - 1);

  const int sh = (ch >= CC / 2) ? ((ch - CC / 2) >> 4) : 0;  // 0 => identity
  const int q  = (l + (sh << 2)) & 63;   // rotated input slot (bijection in wave)

  const int base = bc << 10;
  const int o4 = ((l >> 4) << 8) | (h0 << 4) | (l & 15);
  const int i4 = ((q >> 4) << 8) | (h0 << 4) | (q & 15);

  const f32x4 v = __builtin_nontemporal_load(&in[base + i4]);
  __builtin_nontemporal_store(v, &out[base + o4]);
}

extern "C" void kernel_launch(void* const* d_in, const int* in_sizes, int n_in,
                              void* d_out, int out_size, void* d_ws, size_t ws_size,
                              hipStream_t stream) {
  const f32x4* in = (const f32x4*)d_in[0];
  f32x4* out = (f32x4*)d_out;
  const int total4 = in_sizes[0] / 4;       // 8,388,608 float4
  const int blocks = total4 / 256;          // 32,768
  GlobalShift2dV2Portion_kernel<<<blocks, 256, 0, stream>>>(in, out);
}